// Round 13
// baseline (84.208 us; speedup 1.0000x reference)
//
#include <hip/hip_runtime.h>
#include <hip/hip_bf16.h>

#define Hn 224
#define HWn (224*224)
#define B_ 16
#define CIN_ 64
#define COUT_ 64
#define PR 230            // padded rows: 2 top + 224 + 4 bottom
#define PC 240            // padded row stride in floats
#define PHW (PR*PC)
#define GUARD 1024        // floats of guard before Sp (covers row -1 reads)

typedef __attribute__((ext_vector_type(4)))  float f32x4;
typedef __attribute__((ext_vector_type(8)))  short bf16x8;
typedef __attribute__((ext_vector_type(16))) float f32x16;

// Kernel 1: S'[b, y+2, x+2] = sum_ic x[b,ic,y,x]  (padded f32 layout)
// + inline halo replication (edge threads write their circular-wrap copies).
// x loads NON-TEMPORAL (R12 win): x skips L3 so dirty 'out' lines are never
// evicted by the read stream (no evict-writeback coupling).
__global__ __launch_bounds__(256) void chan_sum_kernel(const float* __restrict__ x,
                                                       float* __restrict__ Sp) {
    int idx = blockIdx.x * 256 + threadIdx.x;
    const int npix4 = B_ * HWn / 4;
    if (idx >= npix4) return;
    const int s4 = HWn / 4;
    int b  = idx / s4;
    int p4 = idx - b * s4;
    const f32x4* xb = (const f32x4*)x + (size_t)b * CIN_ * s4 + p4;

    f32x4 a0 = __builtin_nontemporal_load(xb + 0 * s4);
    f32x4 a1 = __builtin_nontemporal_load(xb + 1 * s4);
    f32x4 a2 = __builtin_nontemporal_load(xb + 2 * s4);
    f32x4 a3 = __builtin_nontemporal_load(xb + 3 * s4);
    #pragma unroll 4
    for (int c = 4; c < CIN_; c += 4) {
        a0 += __builtin_nontemporal_load(xb + (size_t)(c + 0) * s4);
        a1 += __builtin_nontemporal_load(xb + (size_t)(c + 1) * s4);
        a2 += __builtin_nontemporal_load(xb + (size_t)(c + 2) * s4);
        a3 += __builtin_nontemporal_load(xb + (size_t)(c + 3) * s4);
    }
    f32x4 r = (a0 + a1) + (a2 + a3);
    float v0 = r.x, v1 = r.y, v2 = r.z, v3 = r.w;

    int y  = p4 / 56;                 // 0..223
    int x0 = (p4 - y * 56) * 4;       // 0..220 step 4
    float* Sb = Sp + (size_t)b * PHW;

    float* dst = Sb + (size_t)(y + 2) * PC + 2 + x0;
    dst[0] = v0; dst[1] = v1; dst[2] = v2; dst[3] = v3;

    // row halos: y 0..3 -> pr 226..229 ; y 222,223 -> pr 0,1
    if (y < 4) {
        float* d = Sb + (size_t)(y + 226) * PC + 2 + x0;
        d[0] = v0; d[1] = v1; d[2] = v2; d[3] = v3;
    }
    if (y >= 222) {
        float* d = Sb + (size_t)(y - 222) * PC + 2 + x0;
        d[0] = v0; d[1] = v1; d[2] = v2; d[3] = v3;
    }
    // col halos: x 0..3 -> p 226..229 ; x 222,223 -> p 0,1  (+ corners)
    if (x0 == 0) {
        float* d = Sb + (size_t)(y + 2) * PC + 226;
        d[0] = v0; d[1] = v1; d[2] = v2; d[3] = v3;
        if (y < 4) {
            float* e = Sb + (size_t)(y + 226) * PC + 226;
            e[0] = v0; e[1] = v1; e[2] = v2; e[3] = v3;
        }
        if (y >= 222) {
            float* e = Sb + (size_t)(y - 222) * PC + 226;
            e[0] = v0; e[1] = v1; e[2] = v2; e[3] = v3;
        }
    }
    if (x0 == 220) {                   // x 222,223 live in lanes v2,v3
        float* d = Sb + (size_t)(y + 2) * PC;
        d[0] = v2; d[1] = v3;
        if (y < 4) {
            float* e = Sb + (size_t)(y + 226) * PC;
            e[0] = v2; e[1] = v3;
        }
        if (y >= 222) {
            float* e = Sb + (size_t)(y - 222) * PC;
            e[0] = v2; e[1] = v3;
        }
    }
}

// Conv via MFMA, weights built in-block from K (no wprep kernel / W buffer):
// out[b, oc, y, x0+n] = sum_k W'[oc][k] * patch[k][n],  k = ky*8+kx (zero pad).
// patch[k][n] = Sp[b][y + 6 - ky][x0 + 6 - kx + n].
// Stores NORMAL (allocating); x was nt so out can stay L3-resident.
__global__ __launch_bounds__(128, 4) void conv_mfma(const float* __restrict__ Sp,
                                                    const float* __restrict__ K,
                                                    float* __restrict__ out) {
    const int yg = blockIdx.x;           // 0..111
    const int b  = blockIdx.y;           // 0..15
    const int wv = threadIdx.x >> 6;     // 0..1
    const int l  = threadIdx.x & 63;
    const int y   = yg * 2 + wv;
    const int lo5 = l & 31;
    const int hi  = l >> 5;

    // A fragments straight from K: lane holds A[m][k=c*16+hi*8+j], j=0..7.
    // ky = (c*16+hi*8+j)>>3 = 2c+hi, kx = j; zero at kx==7 or ky==7.
    // All blocks read the same 12.5KB slice of K -> L2-broadcast.
    bf16x8 afrag[2][4];
    #pragma unroll
    for (int g = 0; g < 2; ++g) {
        const int m = g * 32 + lo5;
        #pragma unroll
        for (int c = 0; c < 4; ++c) {
            const int ky = 2 * c + hi;
            const float* kp = K + (size_t)m * (CIN_ * 49) + ky * 7;
            const bool ok = (ky < 7);
            float f0 = ok ? kp[0] : 0.f, f1 = ok ? kp[1] : 0.f;
            float f2 = ok ? kp[2] : 0.f, f3 = ok ? kp[3] : 0.f;
            float f4 = ok ? kp[4] : 0.f, f5 = ok ? kp[5] : 0.f;
            float f6 = ok ? kp[6] : 0.f, f7 = 0.f;
            union { int i[4]; bf16x8 v; } au;
            asm("v_cvt_pk_bf16_f32 %0, %1, %2" : "=v"(au.i[0]) : "v"(f0), "v"(f1));
            asm("v_cvt_pk_bf16_f32 %0, %1, %2" : "=v"(au.i[1]) : "v"(f2), "v"(f3));
            asm("v_cvt_pk_bf16_f32 %0, %1, %2" : "=v"(au.i[2]) : "v"(f4), "v"(f5));
            asm("v_cvt_pk_bf16_f32 %0, %1, %2" : "=v"(au.i[3]) : "v"(f6), "v"(f7));
            afrag[g][c] = au.v;
        }
    }

    const float* Sb = Sp + (size_t)b * PHW;
    float* outb = out + (size_t)b * COUT_ * HWn + (size_t)y * Hn;

    for (int xt = 0; xt < 7; ++xt) {
        const int x0 = xt * 32;

        f32x16 acc0, acc1;
        #pragma unroll
        for (int i = 0; i < 16; ++i) { acc0[i] = 0.0f; acc1[i] = 0.0f; }

        #pragma unroll
        for (int c = 0; c < 4; ++c) {
            // B fragment: lane holds B^T[n=lo5][k = c*16 + hi*8 + 2j + {0,1}]
            // k -> ky = 2c + hi, kx = 2j (+1 for hi half of pair)
            const int rowg = y + 6 - (2 * c + hi);
            const float* rp = Sb + rowg * PC + x0 + 6 + lo5;
            union { int i[4]; bf16x8 v; } bu;
            #pragma unroll
            for (int j = 0; j < 4; ++j) {
                float flo = rp[-(2 * j)];        // kx = 2j
                float fhi = rp[-(2 * j) - 1];    // kx = 2j+1
                asm("v_cvt_pk_bf16_f32 %0, %1, %2" : "=v"(bu.i[j]) : "v"(flo), "v"(fhi));
            }
            acc0 = __builtin_amdgcn_mfma_f32_32x32x16_bf16(afrag[0][c], bu.v, acc0, 0, 0, 0);
            acc1 = __builtin_amdgcn_mfma_f32_32x32x16_bf16(afrag[1][c], bu.v, acc1, 0, 0, 0);
        }

        // C/D layout: col = lo5 (pixel), row = (r&3) + 8*(r>>2) + 4*hi (oc)
        #pragma unroll
        for (int r = 0; r < 16; ++r) {
            const int row = (r & 3) + 8 * (r >> 2) + 4 * hi;
            outb[(size_t)row        * HWn + x0 + lo5] = acc0[r];
            outb[(size_t)(32 + row) * HWn + x0 + lo5] = acc1[r];
        }
    }
}

extern "C" void kernel_launch(void* const* d_in, const int* in_sizes, int n_in,
                              void* d_out, int out_size, void* d_ws, size_t ws_size,
                              hipStream_t stream) {
    const float* x = (const float*)d_in[0];   // [16,64,224,224] f32
    const float* K = (const float*)d_in[1];   // [64,64,7,7] f32
    float* out = (float*)d_out;               // [16,64,224,224] f32
    float* Sp = (float*)d_ws + GUARD;         // padded S' with guard

    const int npix4 = B_ * HWn / 4;
    chan_sum_kernel<<<(npix4 + 255) / 256, 256, 0, stream>>>(x, Sp);

    dim3 g2(112, 16);
    conv_mfma<<<g2, 128, 0, stream>>>(Sp, K, out);
}